// Round 3
// baseline (243.460 us; speedup 1.0000x reference)
//
#include <hip/hip_runtime.h>
#include <math.h>

// Problem constants: B=1024, N=200, E=128, fp32.
constexpr int Bc = 1024;
constexpr int Nc = 200;
constexpr int Ec = 128;
constexpr int ROWS   = 5;  // rows per 32-lane group
constexpr int CHUNKS = 5;  // 5 chunks * 8 groups * 5 rows = 200 rows/batch

// K1: grid (B, CHUNKS) x 256 threads. 8 groups of 32 lanes per block; each
// group computes ROWS rows. No __syncthreads anywhere — pure streaming.
// Writes softmax logits to xs_ws (d_ws) and out_dist*mask to os_out (d_out).
// __launch_bounds__(256,4): 128-VGPR budget so all 10 float4 loads stay in
// flight (R2's 64-VGPR allocation serialized them -> latency-bound at 15% BW).
__global__ __launch_bounds__(256, 4) void dist_part(
    const float* __restrict__ q,      // (B,E)
    const float* __restrict__ q_p,    // (B,E)
    const float* __restrict__ m,      // (B,N,E)
    const float* __restrict__ m_c,    // (B,N,E)
    const float* __restrict__ A1,     // (E)
    const float* __restrict__ A2,     // (E)
    const float* __restrict__ biases, // (B,N)
    const float* __restrict__ mask,   // (B,N)
    float* __restrict__ xs_ws,        // (B,N) softmax logits -> d_ws
    float* __restrict__ os_out)       // (B,N) out_dist*mask  -> d_out
{
    const int b     = blockIdx.x;
    const int chunk = blockIdx.y;
    const int tid   = threadIdx.x;
    const int hw    = tid >> 5;
    const int lane  = tid & 31;
    const int e0    = lane * 4;
    const int n0    = chunk * (8 * ROWS) + hw * ROWS;

    const float4 qv  = *reinterpret_cast<const float4*>(q   + (size_t)b * Ec + e0);
    const float4 qpv = *reinterpret_cast<const float4*>(q_p + (size_t)b * Ec + e0);
    const float4 a1v = *reinterpret_cast<const float4*>(A1  + e0);
    const float4 a2v = *reinterpret_cast<const float4*>(A2  + e0);

    const float* mb  = m   + (size_t)b * Nc * Ec + (size_t)n0 * Ec;
    const float* mcb = m_c + (size_t)b * Nc * Ec + (size_t)n0 * Ec;

    // Issue all 10 independent float4 loads up front.
    float4 mv[ROWS], mcv[ROWS];
#pragma unroll
    for (int r = 0; r < ROWS; ++r)
        mv[r]  = *reinterpret_cast<const float4*>(mb  + (size_t)r * Ec + e0);
#pragma unroll
    for (int r = 0; r < ROWS; ++r)
        mcv[r] = *reinterpret_cast<const float4*>(mcb + (size_t)r * Ec + e0);

    float s_att[ROWS], s_out[ROWS];
#pragma unroll
    for (int r = 0; r < ROWS; ++r) {
        float sa = 0.f, so = 0.f;
#define COMP(c) {                                                        \
        float t1 = (qv.c  - mv[r].c)  * a1v.c;  sa = fmaf(t1, t1, sa);   \
        float t2 = (qpv.c - mv[r].c)  * a2v.c;  sa = fmaf(t2, t2, sa);   \
        float u1 = (qv.c  - mcv[r].c) * a1v.c;  so = fmaf(u1, u1, so);   \
        float u2 = (qpv.c - mcv[r].c) * a2v.c;  so = fmaf(u2, u2, so); }
        COMP(x) COMP(y) COMP(z) COMP(w)
#undef COMP
        s_att[r] = sa;
        s_out[r] = so;
    }

    // 10 interleaved shuffle-reduce chains (xor <=16 stays in each 32-half).
#pragma unroll
    for (int off = 16; off > 0; off >>= 1) {
#pragma unroll
        for (int r = 0; r < ROWS; ++r) {
            s_att[r] += __shfl_xor(s_att[r], off);
            s_out[r] += __shfl_xor(s_out[r], off);
        }
    }

    if (lane == 0) {
#pragma unroll
        for (int r = 0; r < ROWS; ++r) {
            const int n = n0 + r;
            const float bb = biases[(size_t)b * Nc + n];
            const float mk = mask[(size_t)b * Nc + n];
            xs_ws[(size_t)b * Nc + n]  = -(s_att[r] + 2.f * bb) * mk;
            os_out[(size_t)b * Nc + n] =  (s_out[r] + 2.f * bb) * mk;
        }
    }
}

// K2: one block per batch; softmax over the 200 logits, scale os, write out.
__global__ __launch_bounds__(256) void softmax_fin(
    const float* __restrict__ xs_ws,  // (B,N) logits
    float* __restrict__ out)          // (B,N) in: out_dist*mask, out: result
{
    const int b   = blockIdx.x;
    const int tid = threadIdx.x;
    __shared__ float red_s[8];

    const float x  = (tid < Nc) ? xs_ws[(size_t)b * Nc + tid] : -INFINITY;
    const float os = (tid < Nc) ? out[(size_t)b * Nc + tid]   : 0.f;

    float wmax = x;
#pragma unroll
    for (int off = 32; off > 0; off >>= 1)
        wmax = fmaxf(wmax, __shfl_xor(wmax, off));
    if ((tid & 63) == 0) red_s[tid >> 6] = wmax;
    __syncthreads();
    const float gmax = fmaxf(fmaxf(red_s[0], red_s[1]), fmaxf(red_s[2], red_s[3]));

    const float ex = (tid < Nc) ? expf(x - gmax) : 0.f;
    float wsum = ex;
#pragma unroll
    for (int off = 32; off > 0; off >>= 1)
        wsum += __shfl_xor(wsum, off);
    if ((tid & 63) == 0) red_s[4 + (tid >> 6)] = wsum;
    __syncthreads();
    const float gsum = (red_s[4] + red_s[5]) + (red_s[6] + red_s[7]);

    if (tid < Nc)
        out[(size_t)b * Nc + tid] = os * (ex / gsum);
}

extern "C" void kernel_launch(void* const* d_in, const int* in_sizes, int n_in,
                              void* d_out, int out_size, void* d_ws, size_t ws_size,
                              hipStream_t stream) {
    const float* q      = (const float*)d_in[0];
    const float* q_p    = (const float*)d_in[1];
    const float* m      = (const float*)d_in[2];
    const float* m_c    = (const float*)d_in[3];
    const float* A1     = (const float*)d_in[4];
    const float* A2     = (const float*)d_in[5];
    const float* biases = (const float*)d_in[6];
    const float* mask   = (const float*)d_in[7];
    float* out   = (float*)d_out;
    float* xs_ws = (float*)d_ws;   // Bc*Nc floats = 800 KiB

    dim3 grid1(Bc, CHUNKS);
    dist_part<<<grid1, 256, 0, stream>>>(q, q_p, m, m_c, A1, A2, biases, mask,
                                         xs_ws, out);
    softmax_fin<<<Bc, 256, 0, stream>>>(xs_ws, out);
}